// Round 1
// baseline (1928.216 us; speedup 1.0000x reference)
//
#include <hip/hip_runtime.h>
#include <hip/hip_bf16.h>

#define B_    4
#define C_    128
#define HW_   16384
#define K_    1024
#define OUTC_ 256
#define NEG_  (-10000000.0f)
#define SCALE_ 0.08838834764831845f   // 128^-0.5

using bf16 = __hip_bfloat16;

__device__ __forceinline__ void storev(float* p, float v) { *p = v; }
__device__ __forceinline__ void storev(bf16* p, float v)  { *p = __float2bfloat16(v); }

// ---------------------------------------------------------------------------
// 128x128 conv-bn-relu layer on a 32-position LDS tile, 256 threads.
// X layout: [c][p] with stride 33 (bank-conflict-free). thread t: o = t&127
// computes output channel o for 16 positions (half = t>>7).
// ---------------------------------------------------------------------------
__device__ __forceinline__ void layer128_lds(const float* __restrict__ Xs, float* __restrict__ Ys,
                                             const float* __restrict__ W,
                                             const float* __restrict__ sc, const float* __restrict__ sh)
{
    const int t = threadIdx.x;
    const int o = t & 127;
    const int half = t >> 7;
    float acc[16];
#pragma unroll
    for (int p = 0; p < 16; ++p) acc[p] = 0.f;
    const float* wrow  = W + o * 128;
    const float* xbase = Xs + half * 16;
    for (int c = 0; c < 128; c += 4) {
        const float4 w4 = *(const float4*)(wrow + c);
        const float wj[4] = {w4.x, w4.y, w4.z, w4.w};
#pragma unroll
        for (int j = 0; j < 4; ++j) {
            const float* xr = xbase + (c + j) * 33;   // broadcast reads (wave-uniform addr)
#pragma unroll
            for (int p = 0; p < 16; ++p) acc[p] += wj[j] * xr[p];
        }
    }
    const float s = sc[o], h = sh[o];
    float* yb = Ys + o * 33 + half * 16;
#pragma unroll
    for (int p = 0; p < 16; ++p) yb[p] = fmaxf(fmaf(s, acc[p], h), 0.f);
}

// Same compute, but stores transposed to global [pos][128] (float or bf16).
template <typename OutT>
__device__ __forceinline__ void layer128_store(const float* __restrict__ Xs, OutT* __restrict__ outp,
                                               const float* __restrict__ W,
                                               const float* __restrict__ sc, const float* __restrict__ sh)
{
    const int t = threadIdx.x;
    const int o = t & 127;
    const int half = t >> 7;
    float acc[16];
#pragma unroll
    for (int p = 0; p < 16; ++p) acc[p] = 0.f;
    const float* wrow  = W + o * 128;
    const float* xbase = Xs + half * 16;
    for (int c = 0; c < 128; c += 4) {
        const float4 w4 = *(const float4*)(wrow + c);
        const float wj[4] = {w4.x, w4.y, w4.z, w4.w};
#pragma unroll
        for (int j = 0; j < 4; ++j) {
            const float* xr = xbase + (c + j) * 33;
#pragma unroll
            for (int p = 0; p < 16; ++p) acc[p] += wj[j] * xr[p];
        }
    }
    const float s = sc[o], h = sh[o];
#pragma unroll
    for (int p = 0; p < 16; ++p) {
        float v = fmaxf(fmaf(s, acc[p], h), 0.f);
        storev(&outp[(size_t)(half * 16 + p) * 128 + o], v);   // coalesced over o
    }
}

// ---------------------------------------------------------------------------
// Kernel 1: k (2 layers) and v (1 layer) projections -> kbuf/vbuf [b][k][c] f32
// grid (K/32, B), 256 threads
// ---------------------------------------------------------------------------
__global__ __launch_bounds__(256) void kv_proj_kernel(
    const float* __restrict__ key, const float* __restrict__ val,
    const float* __restrict__ Wk1, const float* __restrict__ sk1, const float* __restrict__ bk1,
    const float* __restrict__ Wk2, const float* __restrict__ sk2, const float* __restrict__ bk2,
    const float* __restrict__ Wv,  const float* __restrict__ sv,  const float* __restrict__ bv,
    float* __restrict__ kbuf, float* __restrict__ vbuf)
{
    __shared__ __align__(16) float X[128 * 33];
    __shared__ __align__(16) float Y[128 * 33];
    const int p0 = blockIdx.x * 32;
    const int b  = blockIdx.y;
    const int t  = threadIdx.x;

    for (int e = t; e < 4096; e += 256) {
        int c = e >> 5, p = e & 31;
        X[c * 33 + p] = key[(size_t)(b * 128 + c) * K_ + p0 + p];
    }
    __syncthreads();
    layer128_lds(X, Y, Wk1, sk1, bk1);
    __syncthreads();
    layer128_store(Y, kbuf + (size_t)(b * K_ + p0) * 128, Wk2, sk2, bk2);
    __syncthreads();
    for (int e = t; e < 4096; e += 256) {
        int c = e >> 5, p = e & 31;
        X[c * 33 + p] = val[(size_t)(b * 128 + c) * K_ + p0 + p];
    }
    __syncthreads();
    layer128_store(X, vbuf + (size_t)(b * K_ + p0) * 128, Wv, sv, bv);
}

// ---------------------------------------------------------------------------
// Kernel 2: q projection (2 layers) -> qbuf [b][p][c] bf16
// grid (HW/32, B), 256 threads
// ---------------------------------------------------------------------------
__global__ __launch_bounds__(256) void q_proj_kernel(
    const float* __restrict__ query,
    const float* __restrict__ Wq1, const float* __restrict__ sq1, const float* __restrict__ bq1,
    const float* __restrict__ Wq2, const float* __restrict__ sq2, const float* __restrict__ bq2,
    bf16* __restrict__ qbuf)
{
    __shared__ __align__(16) float X[128 * 33];
    __shared__ __align__(16) float Y[128 * 33];
    const int p0 = blockIdx.x * 32;
    const int b  = blockIdx.y;
    const int t  = threadIdx.x;

    for (int e = t; e < 4096; e += 256) {
        int c = e >> 5, p = e & 31;
        X[c * 33 + p] = query[(size_t)(b * 128 + c) * HW_ + p0 + p];
    }
    __syncthreads();
    layer128_lds(X, Y, Wq1, sq1, bq1);
    __syncthreads();
    layer128_store(Y, qbuf + (size_t)(b * HW_ + p0) * 128, Wq2, sq2, bq2);
}

// ---------------------------------------------------------------------------
// Kernel 3: attention. One block = 8 queries x all 1024 keys. Two-pass softmax
// with sim tile in LDS (f32). grid (HW/8, B), 256 threads.
// ---------------------------------------------------------------------------
__global__ __launch_bounds__(256) void attn_kernel(
    const bf16* __restrict__ qbuf, const float* __restrict__ kbuf, const float* __restrict__ vbuf,
    const int* __restrict__ mask, bf16* __restrict__ ctxbuf)
{
    __shared__ __align__(16) float qs[8 * 128];
    __shared__ __align__(16) float sim[8 * 1024];
    __shared__ float Sinv[8];
    const int q0 = blockIdx.x * 8;
    const int b  = blockIdx.y;
    const int t  = threadIdx.x;

    for (int e = t; e < 1024; e += 256) {
        int q = e >> 7, c = e & 127;
        qs[q * 128 + c] = __bfloat162float(qbuf[(size_t)(b * HW_ + q0 + q) * 128 + c]);
    }
    __syncthreads();

    // --- sim = scale * q.k^T, masked. thread t handles keys t, t+256, t+512, t+768
    {
        float acc[4][8];
#pragma unroll
        for (int kk = 0; kk < 4; ++kk)
#pragma unroll
            for (int q = 0; q < 8; ++q) acc[kk][q] = 0.f;
        const float* kb = kbuf + (size_t)b * K_ * 128;
        for (int c = 0; c < 128; c += 4) {
            float4 kv[4];
#pragma unroll
            for (int kk = 0; kk < 4; ++kk)
                kv[kk] = *(const float4*)(kb + (size_t)(t + kk * 256) * 128 + c);
#pragma unroll
            for (int j = 0; j < 4; ++j) {
#pragma unroll
                for (int q = 0; q < 8; ++q) {
                    const float qv = qs[q * 128 + c + j];
                    acc[0][q] += qv * ((const float*)&kv[0])[j];
                    acc[1][q] += qv * ((const float*)&kv[1])[j];
                    acc[2][q] += qv * ((const float*)&kv[2])[j];
                    acc[3][q] += qv * ((const float*)&kv[3])[j];
                }
            }
        }
#pragma unroll
        for (int kk = 0; kk < 4; ++kk) {
            const int k = t + kk * 256;
            const bool m = mask[b * K_ + k] != 0;
#pragma unroll
            for (int q = 0; q < 8; ++q)
                sim[q * 1024 + k] = m ? acc[kk][q] * SCALE_ : NEG_;
        }
    }
    __syncthreads();

    // --- softmax per row (wave w handles rows w and w+4)
    {
        const int wv = t >> 6, lane = t & 63;
#pragma unroll
        for (int qi = 0; qi < 2; ++qi) {
            const int q = wv + qi * 4;
            float* row = sim + q * 1024;
            float v[16];
            float mx = -3.0e38f;
#pragma unroll
            for (int j = 0; j < 16; ++j) { v[j] = row[lane + 64 * j]; mx = fmaxf(mx, v[j]); }
            for (int m = 32; m >= 1; m >>= 1) mx = fmaxf(mx, __shfl_xor(mx, m, 64));
            float s = 0.f;
#pragma unroll
            for (int j = 0; j < 16; ++j) { float e = __expf(v[j] - mx); row[lane + 64 * j] = e; s += e; }
            for (int m = 32; m >= 1; m >>= 1) s += __shfl_xor(s, m, 64);
            if (lane == 0) Sinv[q] = 1.f / s;
        }
    }
    __syncthreads();

    // --- ctx = attn @ v : thread t owns channel c = t&127, half of the keys
    {
        const int c = t & 127, half = t >> 7;
        float acc[8];
#pragma unroll
        for (int q = 0; q < 8; ++q) acc[q] = 0.f;
        const float* vb   = vbuf + ((size_t)b * K_ + half * 512) * 128 + c;
        const float* simh = sim + half * 512;
        for (int k = 0; k < 512; k += 4) {
            float vv[4];
#pragma unroll
            for (int kk = 0; kk < 4; ++kk) vv[kk] = vb[(size_t)(k + kk) * 128];
#pragma unroll
            for (int q = 0; q < 8; ++q) {
                const float4 s4 = *(const float4*)(simh + q * 1024 + k);
                acc[q] += s4.x * vv[0] + s4.y * vv[1] + s4.z * vv[2] + s4.w * vv[3];
            }
        }
        __syncthreads();
        if (half == 1) {
#pragma unroll
            for (int q = 0; q < 8; ++q) sim[q * 128 + c] = acc[q];
        }
        __syncthreads();
        if (half == 0) {
#pragma unroll
            for (int q = 0; q < 8; ++q) {
                const float v = (acc[q] + sim[q * 128 + c]) * Sinv[q];
                ctxbuf[(size_t)(b * HW_ + q0 + q) * 128 + c] = __float2bfloat16(v);
            }
        }
    }
}

// ---------------------------------------------------------------------------
// Kernel 4: ctx2 = conv_bn_relu(ctx, Wo) ; out = conv_bn_relu([ctx2;query], Wb)
// grid (HW/32, B), 256 threads
// ---------------------------------------------------------------------------
__global__ __launch_bounds__(256) void final_kernel(
    const bf16* __restrict__ ctxbuf, const float* __restrict__ query,
    const float* __restrict__ Wo, const float* __restrict__ so, const float* __restrict__ bo,
    const float* __restrict__ Wb, const float* __restrict__ sb, const float* __restrict__ bb,
    float* __restrict__ out)
{
    __shared__ __align__(16) float Xs[128 * 33];
    __shared__ __align__(16) float Ys[128 * 33];
    const int p0 = blockIdx.x * 32;
    const int b  = blockIdx.y;
    const int t  = threadIdx.x;

    for (int e = t; e < 4096; e += 256) {
        int p = e >> 7, c = e & 127;
        Xs[c * 33 + p] = __bfloat162float(ctxbuf[(size_t)(b * HW_ + p0 + p) * 128 + c]);
    }
    __syncthreads();
    layer128_lds(Xs, Ys, Wo, so, bo);      // Ys = ctx2 tile
    __syncthreads();
    for (int e = t; e < 4096; e += 256) {
        int c = e >> 5, p = e & 31;
        Xs[c * 33 + p] = query[(size_t)(b * 128 + c) * HW_ + p0 + p];
    }
    __syncthreads();

    // bottleneck: 256 outputs. thread t: position p = t&31, output group jg = t>>5
    const int p = t & 31, jg = t >> 5;
    float acc[32];
#pragma unroll
    for (int i = 0; i < 32; ++i) acc[i] = 0.f;
    for (int c = 0; c < 128; c += 4) {
        float yv[4], xv[4];
#pragma unroll
        for (int j = 0; j < 4; ++j) { yv[j] = Ys[(c + j) * 33 + p]; xv[j] = Xs[(c + j) * 33 + p]; }
#pragma unroll
        for (int i = 0; i < 32; ++i) {
            const int j = jg * 32 + i;
            const float4 wy = *(const float4*)(Wb + (size_t)j * 256 + c);
            const float4 wx = *(const float4*)(Wb + (size_t)j * 256 + 128 + c);
            acc[i] += wy.x * yv[0] + wy.y * yv[1] + wy.z * yv[2] + wy.w * yv[3]
                    + wx.x * xv[0] + wx.y * xv[1] + wx.z * xv[2] + wx.w * xv[3];
        }
    }
#pragma unroll
    for (int i = 0; i < 32; ++i) {
        const int j = jg * 32 + i;
        out[(size_t)(b * 256 + j) * HW_ + p0 + p] = fmaxf(fmaf(sb[j], acc[i], bb[j]), 0.f);
    }
}

// ---------------------------------------------------------------------------
extern "C" void kernel_launch(void* const* d_in, const int* in_sizes, int n_in,
                              void* d_out, int out_size, void* d_ws, size_t ws_size,
                              hipStream_t stream)
{
    const float* query = (const float*)d_in[0];
    const float* key   = (const float*)d_in[1];
    const float* val   = (const float*)d_in[2];
    const int*   mask  = (const int*)  d_in[3];
    const float* Wq1 = (const float*)d_in[4];  const float* sq1 = (const float*)d_in[5];  const float* bq1 = (const float*)d_in[6];
    const float* Wq2 = (const float*)d_in[7];  const float* sq2 = (const float*)d_in[8];  const float* bq2 = (const float*)d_in[9];
    const float* Wk1 = (const float*)d_in[10]; const float* sk1 = (const float*)d_in[11]; const float* bk1 = (const float*)d_in[12];
    const float* Wk2 = (const float*)d_in[13]; const float* sk2 = (const float*)d_in[14]; const float* bk2 = (const float*)d_in[15];
    const float* Wv  = (const float*)d_in[16]; const float* sv  = (const float*)d_in[17]; const float* bv  = (const float*)d_in[18];
    const float* Wo  = (const float*)d_in[19]; const float* so  = (const float*)d_in[20]; const float* bo  = (const float*)d_in[21];
    const float* Wb  = (const float*)d_in[22]; const float* sb  = (const float*)d_in[23]; const float* bb  = (const float*)d_in[24];

    char* ws = (char*)d_ws;
    float* kbuf = (float*)(ws);                 // [B][K][C] f32   : 2 MB
    float* vbuf = (float*)(ws + (2u << 20));    // [B][K][C] f32   : 2 MB
    bf16*  qbuf = (bf16*) (ws + (4u << 20));    // [B][HW][C] bf16 : 16 MB
    bf16*  ctxb = (bf16*) (ws + (20u << 20));   // [B][HW][C] bf16 : 16 MB
    float* outp = (float*)d_out;

    kv_proj_kernel<<<dim3(K_ / 32, B_), dim3(256), 0, stream>>>(
        key, val, Wk1, sk1, bk1, Wk2, sk2, bk2, Wv, sv, bv, kbuf, vbuf);
    q_proj_kernel<<<dim3(HW_ / 32, B_), dim3(256), 0, stream>>>(
        query, Wq1, sq1, bq1, Wq2, sq2, bq2, qbuf);
    attn_kernel<<<dim3(HW_ / 8, B_), dim3(256), 0, stream>>>(
        qbuf, kbuf, vbuf, mask, ctxb);
    final_kernel<<<dim3(HW_ / 32, B_), dim3(256), 0, stream>>>(
        ctxb, query, Wo, so, bo, Wb, sb, bb, outp);
}

// Round 2
// 1036.102 us; speedup vs baseline: 1.8610x; 1.8610x over previous
//
#include <hip/hip_runtime.h>
#include <hip/hip_bf16.h>

#define B_    4
#define C_    128
#define HW_   16384
#define K_    1024
#define OUTC_ 256
#define NEG_  (-10000000.0f)
#define SCALE_ 0.08838834764831845f   // 128^-0.5

using bf16 = __hip_bfloat16;
typedef __bf16 b8v  __attribute__((ext_vector_type(8)));
typedef float  f4v  __attribute__((ext_vector_type(4)));

__device__ __forceinline__ void storev(float* p, float v) { *p = v; }
__device__ __forceinline__ void storev(bf16* p, float v)  { *p = __float2bfloat16(v); }
__device__ __forceinline__ b8v  ldb8(const bf16* p)       { return *(const b8v*)(const void*)p; }

// ---------------------------------------------------------------------------
// 128x128 conv-bn-relu layer on a 32-position LDS tile, 256 threads.
// X layout: [c][p] stride 33. thread t: o = t&127 computes output channel o
// for 16 positions (half = t>>7).
// ---------------------------------------------------------------------------
__device__ __forceinline__ void layer128_lds(const float* __restrict__ Xs, float* __restrict__ Ys,
                                             const float* __restrict__ W,
                                             const float* __restrict__ sc, const float* __restrict__ sh)
{
    const int t = threadIdx.x;
    const int o = t & 127;
    const int half = t >> 7;
    float acc[16];
#pragma unroll
    for (int p = 0; p < 16; ++p) acc[p] = 0.f;
    const float* wrow  = W + o * 128;
    const float* xbase = Xs + half * 16;
    for (int c = 0; c < 128; c += 4) {
        const float4 w4 = *(const float4*)(wrow + c);
        const float wj[4] = {w4.x, w4.y, w4.z, w4.w};
#pragma unroll
        for (int j = 0; j < 4; ++j) {
            const float* xr = xbase + (c + j) * 33;
#pragma unroll
            for (int p = 0; p < 16; ++p) acc[p] += wj[j] * xr[p];
        }
    }
    const float s = sc[o], h = sh[o];
    float* yb = Ys + o * 33 + half * 16;
#pragma unroll
    for (int p = 0; p < 16; ++p) yb[p] = fmaxf(fmaf(s, acc[p], h), 0.f);
}

template <typename OutT>
__device__ __forceinline__ void layer128_store(const float* __restrict__ Xs, OutT* __restrict__ outp,
                                               const float* __restrict__ W,
                                               const float* __restrict__ sc, const float* __restrict__ sh)
{
    const int t = threadIdx.x;
    const int o = t & 127;
    const int half = t >> 7;
    float acc[16];
#pragma unroll
    for (int p = 0; p < 16; ++p) acc[p] = 0.f;
    const float* wrow  = W + o * 128;
    const float* xbase = Xs + half * 16;
    for (int c = 0; c < 128; c += 4) {
        const float4 w4 = *(const float4*)(wrow + c);
        const float wj[4] = {w4.x, w4.y, w4.z, w4.w};
#pragma unroll
        for (int j = 0; j < 4; ++j) {
            const float* xr = xbase + (c + j) * 33;
#pragma unroll
            for (int p = 0; p < 16; ++p) acc[p] += wj[j] * xr[p];
        }
    }
    const float s = sc[o], h = sh[o];
#pragma unroll
    for (int p = 0; p < 16; ++p) {
        float v = fmaxf(fmaf(s, acc[p], h), 0.f);
        storev(&outp[(size_t)(half * 16 + p) * 128 + o], v);   // coalesced over o
    }
}

// ---------------------------------------------------------------------------
// Kernel 1: k (2 layers) -> kbuf [b][k][c] bf16 ; v (1 layer) -> vbuf [b][c][k] bf16
// grid (K/32, B), 256 threads
// ---------------------------------------------------------------------------
__global__ __launch_bounds__(256) void kv_proj_kernel(
    const float* __restrict__ key, const float* __restrict__ val,
    const float* __restrict__ Wk1, const float* __restrict__ sk1, const float* __restrict__ bk1,
    const float* __restrict__ Wk2, const float* __restrict__ sk2, const float* __restrict__ bk2,
    const float* __restrict__ Wv,  const float* __restrict__ sv,  const float* __restrict__ bv,
    bf16* __restrict__ kbuf, bf16* __restrict__ vbuf)
{
    __shared__ __align__(16) float X[128 * 33];
    __shared__ __align__(16) float Y[128 * 33];
    const int p0 = blockIdx.x * 32;
    const int b  = blockIdx.y;
    const int t  = threadIdx.x;

    for (int e = t; e < 4096; e += 256) {
        int c = e >> 5, p = e & 31;
        X[c * 33 + p] = key[(size_t)(b * 128 + c) * K_ + p0 + p];
    }
    __syncthreads();
    layer128_lds(X, Y, Wk1, sk1, bk1);
    __syncthreads();
    layer128_store(Y, kbuf + (size_t)(b * K_ + p0) * 128, Wk2, sk2, bk2);
    __syncthreads();
    for (int e = t; e < 4096; e += 256) {
        int c = e >> 5, p = e & 31;
        X[c * 33 + p] = val[(size_t)(b * 128 + c) * K_ + p0 + p];
    }
    __syncthreads();
    layer128_lds(X, Y, Wv, sv, bv);
    __syncthreads();
    // v transposed out: [c][key] bf16
    for (int e = t; e < 4096; e += 256) {
        int c = e >> 5, p = e & 31;
        vbuf[(size_t)(b * 128 + c) * K_ + p0 + p] = __float2bfloat16(Y[c * 33 + p]);
    }
}

// ---------------------------------------------------------------------------
// Kernel 2: q projection (2 layers) -> qbuf [b][p][c] bf16
// ---------------------------------------------------------------------------
__global__ __launch_bounds__(256) void q_proj_kernel(
    const float* __restrict__ query,
    const float* __restrict__ Wq1, const float* __restrict__ sq1, const float* __restrict__ bq1,
    const float* __restrict__ Wq2, const float* __restrict__ sq2, const float* __restrict__ bq2,
    bf16* __restrict__ qbuf)
{
    __shared__ __align__(16) float X[128 * 33];
    __shared__ __align__(16) float Y[128 * 33];
    const int p0 = blockIdx.x * 32;
    const int b  = blockIdx.y;
    const int t  = threadIdx.x;

    for (int e = t; e < 4096; e += 256) {
        int c = e >> 5, p = e & 31;
        X[c * 33 + p] = query[(size_t)(b * 128 + c) * HW_ + p0 + p];
    }
    __syncthreads();
    layer128_lds(X, Y, Wq1, sq1, bq1);
    __syncthreads();
    layer128_store(Y, qbuf + (size_t)(b * HW_ + p0) * 128, Wq2, sq2, bq2);
}

// ---------------------------------------------------------------------------
// Kernel 3: flash attention via MFMA. Block = 64 queries (wave w -> 16 q),
// loop over 16 chunks of 64 keys. grid (HW/64, B), 256 threads.
//   GEMM1: sim = q[16,128] @ k^T  (A=q from qbuf[q][c], B=k from kbuf[k][c])
//   GEMM2: ctx = P[16,64] @ v     (A=P via LDS round-trip, B=v from vbuf[c][k])
// ---------------------------------------------------------------------------
__global__ __launch_bounds__(256) void attn_kernel(
    const bf16* __restrict__ qbuf, const bf16* __restrict__ kbuf, const bf16* __restrict__ vbuf,
    const int* __restrict__ mask, bf16* __restrict__ ctxbuf)
{
    __shared__ float bias[K_];                 // 0 or NEG per key
    __shared__ __align__(16) __bf16 Pw[4][16 * 72];  // per-wave P tile, stride 72 (144B, 16B-aligned rows)

    const int t    = threadIdx.x;
    const int w    = t >> 6;
    const int lane = t & 63;
    const int m    = lane & 15;     // query-within-wave / key-col / chan-col index
    const int quad = lane >> 4;
    const int q0   = blockIdx.x * 64;
    const int b    = blockIdx.y;

    for (int i = t; i < K_; i += 256)
        bias[i] = (mask[b * K_ + i] != 0) ? 0.f : NEG_;
    __syncthreads();

    // A-frags of q: 4 c-steps, kept all kernel
    b8v qf[4];
    {
        const bf16* qrow = qbuf + ((size_t)b * HW_ + q0 + w * 16 + m) * 128;
#pragma unroll
        for (int s = 0; s < 4; ++s) qf[s] = ldb8(qrow + s * 32 + quad * 8);
    }

    const bf16* kb = kbuf + (size_t)b * K_ * 128;
    const bf16* vb = vbuf + (size_t)b * 128 * K_;

    f4v acc[8];
#pragma unroll
    for (int i = 0; i < 8; ++i) acc[i] = (f4v){0.f, 0.f, 0.f, 0.f};
    float mrow[4] = {-3.0e38f, -3.0e38f, -3.0e38f, -3.0e38f};
    float lrow[4] = {0.f, 0.f, 0.f, 0.f};

    for (int chunk = 0; chunk < 16; ++chunk) {
        const int k0 = chunk * 64;

        // ---- GEMM1: sim tiles (4 N-tiles of 16 keys)
        float sv[4][4];
#pragma unroll
        for (int n = 0; n < 4; ++n) {
            f4v a = (f4v){0.f, 0.f, 0.f, 0.f};
            const bf16* krow = kb + (size_t)(k0 + n * 16 + m) * 128 + quad * 8;
#pragma unroll
            for (int s = 0; s < 4; ++s)
                a = __builtin_amdgcn_mfma_f32_16x16x32_bf16(qf[s], ldb8(krow + s * 32), a, 0, 0, 0);
            const float bv = bias[k0 + n * 16 + m];
#pragma unroll
            for (int r = 0; r < 4; ++r) sv[n][r] = a[r] * SCALE_ + bv;
        }

        // ---- online softmax stats (rows quad*4+r; cols across 16-lane group)
        float mloc[4];
#pragma unroll
        for (int r = 0; r < 4; ++r) {
            mloc[r] = fmaxf(fmaxf(sv[0][r], sv[1][r]), fmaxf(sv[2][r], sv[3][r]));
#pragma unroll
            for (int off = 1; off < 16; off <<= 1)
                mloc[r] = fmaxf(mloc[r], __shfl_xor(mloc[r], off, 64));
        }
        float alpha[4], rs[4];
#pragma unroll
        for (int r = 0; r < 4; ++r) {
            const float mn = fmaxf(mrow[r], mloc[r]);
            alpha[r] = __expf(mrow[r] - mn);
            mrow[r] = mn;
            rs[r] = 0.f;
        }
        // exp + write P to wave-private LDS (row=query, col=key-in-chunk)
#pragma unroll
        for (int n = 0; n < 4; ++n)
#pragma unroll
            for (int r = 0; r < 4; ++r) {
                const float p = __expf(sv[n][r] - mrow[r]);
                rs[r] += p;
                Pw[w][(quad * 4 + r) * 72 + n * 16 + m] = (__bf16)p;
            }
#pragma unroll
        for (int r = 0; r < 4; ++r) {
#pragma unroll
            for (int off = 1; off < 16; off <<= 1)
                rs[r] += __shfl_xor(rs[r], off, 64);
            lrow[r] = lrow[r] * alpha[r] + rs[r];
        }
        // rescale ctx accumulators
#pragma unroll
        for (int ti = 0; ti < 8; ++ti)
#pragma unroll
            for (int r = 0; r < 4; ++r) acc[ti][r] *= alpha[r];

        // wave-local write->read ordering for Pw
        asm volatile("s_waitcnt lgkmcnt(0)" ::: "memory");

        // ---- GEMM2: ctx += P @ v
        b8v pf[2];
#pragma unroll
        for (int s = 0; s < 2; ++s)
            pf[s] = *(const b8v*)(const void*)&Pw[w][m * 72 + s * 32 + quad * 8];
#pragma unroll
        for (int ti = 0; ti < 8; ++ti) {
            const bf16* vrow = vb + (size_t)(ti * 16 + m) * K_ + k0 + quad * 8;
#pragma unroll
            for (int s = 0; s < 2; ++s)
                acc[ti] = __builtin_amdgcn_mfma_f32_16x16x32_bf16(pf[s], ldb8(vrow + s * 32), acc[ti], 0, 0, 0);
        }
    }

    // ---- epilogue: normalize by l, store ctx bf16 [q][c]
    float inv[4];
#pragma unroll
    for (int r = 0; r < 4; ++r) inv[r] = 1.f / lrow[r];
    bf16* crow = ctxbuf + ((size_t)b * HW_ + q0 + w * 16) * 128;
#pragma unroll
    for (int ti = 0; ti < 8; ++ti)
#pragma unroll
        for (int r = 0; r < 4; ++r)
            crow[(size_t)(quad * 4 + r) * 128 + ti * 16 + m] = __float2bfloat16(acc[ti][r] * inv[r]);
}

// ---------------------------------------------------------------------------
// Kernel 4: ctx2 = conv_bn_relu(ctx, Wo) ; out = conv_bn_relu([ctx2;query], Wb)
// ---------------------------------------------------------------------------
__global__ __launch_bounds__(256) void final_kernel(
    const bf16* __restrict__ ctxbuf, const float* __restrict__ query,
    const float* __restrict__ Wo, const float* __restrict__ so, const float* __restrict__ bo,
    const float* __restrict__ Wb, const float* __restrict__ sb, const float* __restrict__ bb,
    float* __restrict__ out)
{
    __shared__ __align__(16) float Xs[128 * 33];
    __shared__ __align__(16) float Ys[128 * 33];
    const int p0 = blockIdx.x * 32;
    const int b  = blockIdx.y;
    const int t  = threadIdx.x;

    for (int e = t; e < 4096; e += 256) {
        int p = e >> 7, c = e & 127;
        Xs[c * 33 + p] = __bfloat162float(ctxbuf[(size_t)(b * HW_ + p0 + p) * 128 + c]);
    }
    __syncthreads();
    layer128_lds(Xs, Ys, Wo, so, bo);      // Ys = ctx2 tile
    __syncthreads();
    for (int e = t; e < 4096; e += 256) {
        int c = e >> 5, p = e & 31;
        Xs[c * 33 + p] = query[(size_t)(b * 128 + c) * HW_ + p0 + p];
    }
    __syncthreads();

    const int p = t & 31, jg = t >> 5;
    float acc[32];
#pragma unroll
    for (int i = 0; i < 32; ++i) acc[i] = 0.f;
    for (int c = 0; c < 128; c += 4) {
        float yv[4], xv[4];
#pragma unroll
        for (int j = 0; j < 4; ++j) { yv[j] = Ys[(c + j) * 33 + p]; xv[j] = Xs[(c + j) * 33 + p]; }
#pragma unroll
        for (int i = 0; i < 32; ++i) {
            const int j = jg * 32 + i;
            const float4 wy = *(const float4*)(Wb + (size_t)j * 256 + c);
            const float4 wx = *(const float4*)(Wb + (size_t)j * 256 + 128 + c);
            acc[i] += wy.x * yv[0] + wy.y * yv[1] + wy.z * yv[2] + wy.w * yv[3]
                    + wx.x * xv[0] + wx.y * xv[1] + wx.z * xv[2] + wx.w * xv[3];
        }
    }
#pragma unroll
    for (int i = 0; i < 32; ++i) {
        const int j = jg * 32 + i;
        out[(size_t)(b * 256 + j) * HW_ + p0 + p] = fmaxf(fmaf(sb[j], acc[i], bb[j]), 0.f);
    }
}

// ---------------------------------------------------------------------------
extern "C" void kernel_launch(void* const* d_in, const int* in_sizes, int n_in,
                              void* d_out, int out_size, void* d_ws, size_t ws_size,
                              hipStream_t stream)
{
    const float* query = (const float*)d_in[0];
    const float* key   = (const float*)d_in[1];
    const float* val   = (const float*)d_in[2];
    const int*   mask  = (const int*)  d_in[3];
    const float* Wq1 = (const float*)d_in[4];  const float* sq1 = (const float*)d_in[5];  const float* bq1 = (const float*)d_in[6];
    const float* Wq2 = (const float*)d_in[7];  const float* sq2 = (const float*)d_in[8];  const float* bq2 = (const float*)d_in[9];
    const float* Wk1 = (const float*)d_in[10]; const float* sk1 = (const float*)d_in[11]; const float* bk1 = (const float*)d_in[12];
    const float* Wk2 = (const float*)d_in[13]; const float* sk2 = (const float*)d_in[14]; const float* bk2 = (const float*)d_in[15];
    const float* Wv  = (const float*)d_in[16]; const float* sv  = (const float*)d_in[17]; const float* bv  = (const float*)d_in[18];
    const float* Wo  = (const float*)d_in[19]; const float* so  = (const float*)d_in[20]; const float* bo  = (const float*)d_in[21];
    const float* Wb  = (const float*)d_in[22]; const float* sb  = (const float*)d_in[23]; const float* bb  = (const float*)d_in[24];

    char* ws = (char*)d_ws;
    bf16* kbuf = (bf16*)(ws);                  // [B][K][C] bf16  : 1 MB
    bf16* vbuf = (bf16*)(ws + (1u << 20));     // [B][C][K] bf16  : 1 MB
    bf16* qbuf = (bf16*)(ws + (2u << 20));     // [B][HW][C] bf16 : 16 MB
    bf16* ctxb = (bf16*)(ws + (18u << 20));    // [B][HW][C] bf16 : 16 MB
    float* outp = (float*)d_out;

    kv_proj_kernel<<<dim3(K_ / 32, B_), dim3(256), 0, stream>>>(
        key, val, Wk1, sk1, bk1, Wk2, sk2, bk2, Wv, sv, bv, kbuf, vbuf);
    q_proj_kernel<<<dim3(HW_ / 32, B_), dim3(256), 0, stream>>>(
        query, Wq1, sq1, bq1, Wq2, sq2, bq2, qbuf);
    attn_kernel<<<dim3(HW_ / 64, B_), dim3(256), 0, stream>>>(
        qbuf, kbuf, vbuf, mask, ctxb);
    final_kernel<<<dim3(HW_ / 32, B_), dim3(256), 0, stream>>>(
        ctxb, query, Wo, so, bo, Wb, sb, bb, outp);
}

// Round 3
// 472.840 us; speedup vs baseline: 4.0779x; 2.1912x over previous
//
#include <hip/hip_runtime.h>
#include <hip/hip_bf16.h>

#define B_    4
#define C_    128
#define HW_   16384
#define K_    1024
#define NEG_  (-10000000.0f)
#define SCALE_ 0.08838834764831845f   // 128^-0.5

using bf16 = __hip_bfloat16;
typedef __bf16 b8v __attribute__((ext_vector_type(8)));
typedef __bf16 b4v __attribute__((ext_vector_type(4)));
typedef __bf16 b2v __attribute__((ext_vector_type(2)));
typedef float  f4v __attribute__((ext_vector_type(4)));

__device__ __forceinline__ b8v ldb8(const void* p) { return *(const b8v*)p; }
__device__ __forceinline__ void storev(float* p, float v) { *p = v; }
__device__ __forceinline__ void storev(bf16* p, float v)  { *p = __float2bfloat16(v); }

// ---------------------------------------------------------------------------
// Weight prep: fold BN scale into rows, convert fp32 -> bf16.
// 3 x 128x128 (Wq1,Wq2,Wo) + 1 x 256x256 (Wb). grid 448x256 exact.
// ---------------------------------------------------------------------------
__global__ __launch_bounds__(256) void wprep_kernel(
    const float* __restrict__ Wq1, const float* __restrict__ sq1,
    const float* __restrict__ Wq2, const float* __restrict__ sq2,
    const float* __restrict__ Wo,  const float* __restrict__ so,
    const float* __restrict__ Wb,  const float* __restrict__ sb,
    __bf16* __restrict__ Wq1p, __bf16* __restrict__ Wq2p,
    __bf16* __restrict__ Wop,  __bf16* __restrict__ Wbp)
{
    const int idx = blockIdx.x * 256 + threadIdx.x;
    if (idx < 16384)      { Wq1p[idx] = (__bf16)(Wq1[idx] * sq1[idx >> 7]); }
    else if (idx < 32768) { const int i = idx - 16384; Wq2p[i] = (__bf16)(Wq2[i] * sq2[i >> 7]); }
    else if (idx < 49152) { const int i = idx - 32768; Wop[i]  = (__bf16)(Wo[i]  * so[i >> 7]); }
    else                  { const int i = idx - 49152; Wbp[i]  = (__bf16)(Wb[i]  * sb[i >> 8]); }
}

// ---------------------------------------------------------------------------
// Transpose query [b][c][p] fp32 -> qt [b][p][c] bf16. grid (HW/64, B).
// ---------------------------------------------------------------------------
__global__ __launch_bounds__(256) void tq_kernel(const float* __restrict__ query,
                                                 bf16* __restrict__ qt)
{
    __shared__ float Xs[64 * 129];
    const int p0 = blockIdx.x * 64, b = blockIdx.y, t = threadIdx.x;
    const int pl = t & 63, cg = t >> 6;
#pragma unroll 4
    for (int i = 0; i < 32; ++i) {
        const int c = cg * 32 + i;
        Xs[pl * 129 + c] = query[(size_t)(b * 128 + c) * HW_ + p0 + pl];
    }
    __syncthreads();
#pragma unroll 4
    for (int it = 0; it < 16; ++it) {
        const int p = it * 4 + cg;
        b2v pk;
        pk[0] = (__bf16)Xs[p * 129 + 2 * pl];
        pk[1] = (__bf16)Xs[p * 129 + 2 * pl + 1];
        *(b2v*)(qt + ((size_t)b * HW_ + p0 + p) * 128 + 2 * pl) = pk;
    }
}

// ---------------------------------------------------------------------------
// kv_proj (unchanged VALU path, small): k (2 layers) -> kbuf [b][k][c] bf16 ;
// v (1 layer) -> vbuf [b][c][k] bf16. grid (K/32, B).
// ---------------------------------------------------------------------------
__device__ __forceinline__ void layer128_lds(const float* __restrict__ Xs, float* __restrict__ Ysh,
                                             const float* __restrict__ W,
                                             const float* __restrict__ sc, const float* __restrict__ sh)
{
    const int t = threadIdx.x;
    const int o = t & 127;
    const int half = t >> 7;
    float acc[16];
#pragma unroll
    for (int p = 0; p < 16; ++p) acc[p] = 0.f;
    const float* wrow  = W + o * 128;
    const float* xbase = Xs + half * 16;
    for (int c = 0; c < 128; c += 4) {
        const float4 w4 = *(const float4*)(wrow + c);
        const float wj[4] = {w4.x, w4.y, w4.z, w4.w};
#pragma unroll
        for (int j = 0; j < 4; ++j) {
            const float* xr = xbase + (c + j) * 33;
#pragma unroll
            for (int p = 0; p < 16; ++p) acc[p] += wj[j] * xr[p];
        }
    }
    const float s = sc[o], h = sh[o];
    float* yb = Ysh + o * 33 + half * 16;
#pragma unroll
    for (int p = 0; p < 16; ++p) yb[p] = fmaxf(fmaf(s, acc[p], h), 0.f);
}

template <typename OutT>
__device__ __forceinline__ void layer128_store(const float* __restrict__ Xs, OutT* __restrict__ outp,
                                               const float* __restrict__ W,
                                               const float* __restrict__ sc, const float* __restrict__ sh)
{
    const int t = threadIdx.x;
    const int o = t & 127;
    const int half = t >> 7;
    float acc[16];
#pragma unroll
    for (int p = 0; p < 16; ++p) acc[p] = 0.f;
    const float* wrow  = W + o * 128;
    const float* xbase = Xs + half * 16;
    for (int c = 0; c < 128; c += 4) {
        const float4 w4 = *(const float4*)(wrow + c);
        const float wj[4] = {w4.x, w4.y, w4.z, w4.w};
#pragma unroll
        for (int j = 0; j < 4; ++j) {
            const float* xr = xbase + (c + j) * 33;
#pragma unroll
            for (int p = 0; p < 16; ++p) acc[p] += wj[j] * xr[p];
        }
    }
    const float s = sc[o], h = sh[o];
#pragma unroll
    for (int p = 0; p < 16; ++p) {
        float v = fmaxf(fmaf(s, acc[p], h), 0.f);
        storev(&outp[(size_t)(half * 16 + p) * 128 + o], v);
    }
}

__global__ __launch_bounds__(256) void kv_proj_kernel(
    const float* __restrict__ key, const float* __restrict__ val,
    const float* __restrict__ Wk1, const float* __restrict__ sk1, const float* __restrict__ bk1,
    const float* __restrict__ Wk2, const float* __restrict__ sk2, const float* __restrict__ bk2,
    const float* __restrict__ Wv,  const float* __restrict__ sv,  const float* __restrict__ bv,
    bf16* __restrict__ kbuf, bf16* __restrict__ vbuf)
{
    __shared__ __align__(16) float X[128 * 33];
    __shared__ __align__(16) float Y[128 * 33];
    const int p0 = blockIdx.x * 32;
    const int b  = blockIdx.y;
    const int t  = threadIdx.x;

    for (int e = t; e < 4096; e += 256) {
        int c = e >> 5, p = e & 31;
        X[c * 33 + p] = key[(size_t)(b * 128 + c) * K_ + p0 + p];
    }
    __syncthreads();
    layer128_lds(X, Y, Wk1, sk1, bk1);
    __syncthreads();
    layer128_store(Y, kbuf + (size_t)(b * K_ + p0) * 128, Wk2, sk2, bk2);
    __syncthreads();
    for (int e = t; e < 4096; e += 256) {
        int c = e >> 5, p = e & 31;
        X[c * 33 + p] = val[(size_t)(b * 128 + c) * K_ + p0 + p];
    }
    __syncthreads();
    layer128_lds(X, Y, Wv, sv, bv);
    __syncthreads();
    for (int e = t; e < 4096; e += 256) {
        int c = e >> 5, p = e & 31;
        vbuf[(size_t)(b * 128 + c) * K_ + p0 + p] = __float2bfloat16(Y[c * 33 + p]);
    }
}

// ---------------------------------------------------------------------------
// q projection via MFMA: 2 chained 128x128 layers over a 128-position tile.
// Wave w owns output channels [32w, 32w+32). B-frags direct from global qt /
// inter-layer LDS [p][o] stride 136. grid (HW/128, B), 256 threads.
// ---------------------------------------------------------------------------
__global__ __launch_bounds__(256, 2) void qproj_kernel(
    const bf16* __restrict__ qt,
    const __bf16* __restrict__ W1, const float* __restrict__ sh1,
    const __bf16* __restrict__ W2, const float* __restrict__ sh2,
    bf16* __restrict__ qbuf)
{
    __shared__ __bf16 Ys[128 * 136];
    const int t = threadIdx.x, w = t >> 6, lane = t & 63;
    const int pl = lane & 15, quad = lane >> 4;
    const int n0 = blockIdx.x * 128, b = blockIdx.y;
    const int ob = 32 * w;

    b8v W1f[2][4], W2f[2][4];
#pragma unroll
    for (int mt = 0; mt < 2; ++mt)
#pragma unroll
        for (int s = 0; s < 4; ++s) {
            W1f[mt][s] = ldb8(W1 + (ob + mt * 16 + pl) * 128 + s * 32 + quad * 8);
            W2f[mt][s] = ldb8(W2 + (ob + mt * 16 + pl) * 128 + s * 32 + quad * 8);
        }

    const bf16* qtb = qt + ((size_t)b * HW_ + n0) * 128;

    f4v acc[2][8];
#pragma unroll
    for (int mt = 0; mt < 2; ++mt)
#pragma unroll
        for (int nt = 0; nt < 8; ++nt) acc[mt][nt] = (f4v){0.f, 0.f, 0.f, 0.f};

#pragma unroll
    for (int s = 0; s < 4; ++s) {
        b8v Bf[8];
#pragma unroll
        for (int nt = 0; nt < 8; ++nt)
            Bf[nt] = ldb8(qtb + (size_t)(nt * 16 + pl) * 128 + s * 32 + quad * 8);
#pragma unroll
        for (int mt = 0; mt < 2; ++mt)
#pragma unroll
            for (int nt = 0; nt < 8; ++nt)
                acc[mt][nt] = __builtin_amdgcn_mfma_f32_16x16x32_bf16(W1f[mt][s], Bf[nt], acc[mt][nt], 0, 0, 0);
    }

    // epilogue 1: shift + relu -> Ys[p][o]
#pragma unroll
    for (int mt = 0; mt < 2; ++mt) {
        const float4 s4 = *(const float4*)(sh1 + ob + mt * 16 + quad * 4);
        const float shf[4] = {s4.x, s4.y, s4.z, s4.w};
#pragma unroll
        for (int nt = 0; nt < 8; ++nt) {
            b4v y;
#pragma unroll
            for (int r = 0; r < 4; ++r) y[r] = (__bf16)fmaxf(acc[mt][nt][r] + shf[r], 0.f);
            *(b4v*)&Ys[(nt * 16 + pl) * 136 + ob + mt * 16 + quad * 4] = y;
        }
    }
    __syncthreads();

    f4v acc2[2][8];
#pragma unroll
    for (int mt = 0; mt < 2; ++mt)
#pragma unroll
        for (int nt = 0; nt < 8; ++nt) acc2[mt][nt] = (f4v){0.f, 0.f, 0.f, 0.f};

#pragma unroll
    for (int s = 0; s < 4; ++s) {
        b8v Bf[8];
#pragma unroll
        for (int nt = 0; nt < 8; ++nt)
            Bf[nt] = *(const b8v*)&Ys[(nt * 16 + pl) * 136 + s * 32 + quad * 8];
#pragma unroll
        for (int mt = 0; mt < 2; ++mt)
#pragma unroll
            for (int nt = 0; nt < 8; ++nt)
                acc2[mt][nt] = __builtin_amdgcn_mfma_f32_16x16x32_bf16(W2f[mt][s], Bf[nt], acc2[mt][nt], 0, 0, 0);
    }

    // epilogue 2: shift + relu -> qbuf [p][c] bf16 (8B packed stores)
    bf16* qb = qbuf + ((size_t)b * HW_ + n0) * 128;
#pragma unroll
    for (int mt = 0; mt < 2; ++mt) {
        const float4 s4 = *(const float4*)(sh2 + ob + mt * 16 + quad * 4);
        const float shf[4] = {s4.x, s4.y, s4.z, s4.w};
#pragma unroll
        for (int nt = 0; nt < 8; ++nt) {
            b4v y;
#pragma unroll
            for (int r = 0; r < 4; ++r) y[r] = (__bf16)fmaxf(acc2[mt][nt][r] + shf[r], 0.f);
            *(b4v*)(qb + (size_t)(nt * 16 + pl) * 128 + ob + mt * 16 + quad * 4) = y;
        }
    }
}

// ---------------------------------------------------------------------------
// Kernel 3: flash attention via MFMA (unchanged from R2).
// ---------------------------------------------------------------------------
__global__ __launch_bounds__(256) void attn_kernel(
    const bf16* __restrict__ qbuf, const bf16* __restrict__ kbuf, const bf16* __restrict__ vbuf,
    const int* __restrict__ mask, bf16* __restrict__ ctxbuf)
{
    __shared__ float bias[K_];
    __shared__ __align__(16) __bf16 Pw[4][16 * 72];

    const int t    = threadIdx.x;
    const int w    = t >> 6;
    const int lane = t & 63;
    const int m    = lane & 15;
    const int quad = lane >> 4;
    const int q0   = blockIdx.x * 64;
    const int b    = blockIdx.y;

    for (int i = t; i < K_; i += 256)
        bias[i] = (mask[b * K_ + i] != 0) ? 0.f : NEG_;
    __syncthreads();

    b8v qf[4];
    {
        const bf16* qrow = qbuf + ((size_t)b * HW_ + q0 + w * 16 + m) * 128;
#pragma unroll
        for (int s = 0; s < 4; ++s) qf[s] = ldb8(qrow + s * 32 + quad * 8);
    }

    const bf16* kb = kbuf + (size_t)b * K_ * 128;
    const bf16* vb = vbuf + (size_t)b * 128 * K_;

    f4v acc[8];
#pragma unroll
    for (int i = 0; i < 8; ++i) acc[i] = (f4v){0.f, 0.f, 0.f, 0.f};
    float mrow[4] = {-3.0e38f, -3.0e38f, -3.0e38f, -3.0e38f};
    float lrow[4] = {0.f, 0.f, 0.f, 0.f};

    for (int chunk = 0; chunk < 16; ++chunk) {
        const int k0 = chunk * 64;

        float sv[4][4];
#pragma unroll
        for (int n = 0; n < 4; ++n) {
            f4v a = (f4v){0.f, 0.f, 0.f, 0.f};
            const bf16* krow = kb + (size_t)(k0 + n * 16 + m) * 128 + quad * 8;
#pragma unroll
            for (int s = 0; s < 4; ++s)
                a = __builtin_amdgcn_mfma_f32_16x16x32_bf16(qf[s], ldb8(krow + s * 32), a, 0, 0, 0);
            const float bv = bias[k0 + n * 16 + m];
#pragma unroll
            for (int r = 0; r < 4; ++r) sv[n][r] = a[r] * SCALE_ + bv;
        }

        float mloc[4];
#pragma unroll
        for (int r = 0; r < 4; ++r) {
            mloc[r] = fmaxf(fmaxf(sv[0][r], sv[1][r]), fmaxf(sv[2][r], sv[3][r]));
#pragma unroll
            for (int off = 1; off < 16; off <<= 1)
                mloc[r] = fmaxf(mloc[r], __shfl_xor(mloc[r], off, 64));
        }
        float alpha[4], rs[4];
#pragma unroll
        for (int r = 0; r < 4; ++r) {
            const float mn = fmaxf(mrow[r], mloc[r]);
            alpha[r] = __expf(mrow[r] - mn);
            mrow[r] = mn;
            rs[r] = 0.f;
        }
#pragma unroll
        for (int n = 0; n < 4; ++n)
#pragma unroll
            for (int r = 0; r < 4; ++r) {
                const float p = __expf(sv[n][r] - mrow[r]);
                rs[r] += p;
                Pw[w][(quad * 4 + r) * 72 + n * 16 + m] = (__bf16)p;
            }
#pragma unroll
        for (int r = 0; r < 4; ++r) {
#pragma unroll
            for (int off = 1; off < 16; off <<= 1)
                rs[r] += __shfl_xor(rs[r], off, 64);
            lrow[r] = lrow[r] * alpha[r] + rs[r];
        }
#pragma unroll
        for (int ti = 0; ti < 8; ++ti)
#pragma unroll
            for (int r = 0; r < 4; ++r) acc[ti][r] *= alpha[r];

        asm volatile("s_waitcnt lgkmcnt(0)" ::: "memory");

        b8v pf[2];
#pragma unroll
        for (int s = 0; s < 2; ++s)
            pf[s] = *(const b8v*)(const void*)&Pw[w][m * 72 + s * 32 + quad * 8];
#pragma unroll
        for (int ti = 0; ti < 8; ++ti) {
            const bf16* vrow = vb + (size_t)(ti * 16 + m) * K_ + k0 + quad * 8;
#pragma unroll
            for (int s = 0; s < 2; ++s)
                acc[ti] = __builtin_amdgcn_mfma_f32_16x16x32_bf16(pf[s], ldb8(vrow + s * 32), acc[ti], 0, 0, 0);
        }
    }

    float inv[4];
#pragma unroll
    for (int r = 0; r < 4; ++r) inv[r] = 1.f / lrow[r];
    bf16* crow = ctxbuf + ((size_t)b * HW_ + q0 + w * 16) * 128;
#pragma unroll
    for (int ti = 0; ti < 8; ++ti)
#pragma unroll
        for (int r = 0; r < 4; ++r)
            crow[(size_t)(quad * 4 + r) * 128 + ti * 16 + m] = __float2bfloat16(acc[ti][r] * inv[r]);
}

// ---------------------------------------------------------------------------
// Final: ctx2 = relu(Wo'@ctx + bo); out = relu(Wb'@[ctx2;qt] + bb) via MFMA.
// Layer1: wave owns o in [32w,+32). Layer2: wave owns o in [64w,+64), K=256
// (first half from LDS ctx2, second half from global qt). grid (HW/128, B).
// ---------------------------------------------------------------------------
__global__ __launch_bounds__(256, 2) void final_kernel(
    const bf16* __restrict__ ctx, const bf16* __restrict__ qt,
    const __bf16* __restrict__ Wop, const float* __restrict__ bo,
    const __bf16* __restrict__ Wbp, const float* __restrict__ bb,
    float* __restrict__ out)
{
    __shared__ __bf16 Ys[128 * 136];
    const int t = threadIdx.x, w = t >> 6, lane = t & 63;
    const int pl = lane & 15, quad = lane >> 4;
    const int n0 = blockIdx.x * 128, b = blockIdx.y;
    const int ob = 32 * w;

    // ---- layer 1
    b8v Wof[2][4];
#pragma unroll
    for (int mt = 0; mt < 2; ++mt)
#pragma unroll
        for (int s = 0; s < 4; ++s)
            Wof[mt][s] = ldb8(Wop + (ob + mt * 16 + pl) * 128 + s * 32 + quad * 8);

    const bf16* cb = ctx + ((size_t)b * HW_ + n0) * 128;

    f4v acc1[2][8];
#pragma unroll
    for (int mt = 0; mt < 2; ++mt)
#pragma unroll
        for (int nt = 0; nt < 8; ++nt) acc1[mt][nt] = (f4v){0.f, 0.f, 0.f, 0.f};

#pragma unroll
    for (int s = 0; s < 4; ++s) {
        b8v Bf[8];
#pragma unroll
        for (int nt = 0; nt < 8; ++nt)
            Bf[nt] = ldb8(cb + (size_t)(nt * 16 + pl) * 128 + s * 32 + quad * 8);
#pragma unroll
        for (int mt = 0; mt < 2; ++mt)
#pragma unroll
            for (int nt = 0; nt < 8; ++nt)
                acc1[mt][nt] = __builtin_amdgcn_mfma_f32_16x16x32_bf16(Wof[mt][s], Bf[nt], acc1[mt][nt], 0, 0, 0);
    }

#pragma unroll
    for (int mt = 0; mt < 2; ++mt) {
        const float4 s4 = *(const float4*)(bo + ob + mt * 16 + quad * 4);
        const float shf[4] = {s4.x, s4.y, s4.z, s4.w};
#pragma unroll
        for (int nt = 0; nt < 8; ++nt) {
            b4v y;
#pragma unroll
            for (int r = 0; r < 4; ++r) y[r] = (__bf16)fmaxf(acc1[mt][nt][r] + shf[r], 0.f);
            *(b4v*)&Ys[(nt * 16 + pl) * 136 + ob + mt * 16 + quad * 4] = y;
        }
    }
    __syncthreads();

    // ---- layer 2: M=256, K=256
    const bf16* qtb = qt + ((size_t)b * HW_ + n0) * 128;
    f4v acc2[4][8];
#pragma unroll
    for (int mt = 0; mt < 4; ++mt)
#pragma unroll
        for (int nt = 0; nt < 8; ++nt) acc2[mt][nt] = (f4v){0.f, 0.f, 0.f, 0.f};

#pragma unroll
    for (int ks = 0; ks < 8; ++ks) {
        b8v Af[4];
#pragma unroll
        for (int mt = 0; mt < 4; ++mt)
            Af[mt] = ldb8(Wbp + (64 * w + mt * 16 + pl) * 256 + ks * 32 + quad * 8);
        b8v Bf[8];
        if (ks < 4) {
#pragma unroll
            for (int nt = 0; nt < 8; ++nt)
                Bf[nt] = *(const b8v*)&Ys[(nt * 16 + pl) * 136 + ks * 32 + quad * 8];
        } else {
#pragma unroll
            for (int nt = 0; nt < 8; ++nt)
                Bf[nt] = ldb8(qtb + (size_t)(nt * 16 + pl) * 128 + (ks - 4) * 32 + quad * 8);
        }
#pragma unroll
        for (int mt = 0; mt < 4; ++mt)
#pragma unroll
            for (int nt = 0; nt < 8; ++nt)
                acc2[mt][nt] = __builtin_amdgcn_mfma_f32_16x16x32_bf16(Af[mt], Bf[nt], acc2[mt][nt], 0, 0, 0);
    }

    // ---- epilogue: fp32 out [b][o][p]
#pragma unroll
    for (int mt = 0; mt < 4; ++mt) {
        const float4 s4 = *(const float4*)(bb + 64 * w + mt * 16 + quad * 4);
        const float shf[4] = {s4.x, s4.y, s4.z, s4.w};
#pragma unroll
        for (int nt = 0; nt < 8; ++nt)
#pragma unroll
            for (int r = 0; r < 4; ++r)
                out[(size_t)(b * 256 + 64 * w + mt * 16 + quad * 4 + r) * HW_ + n0 + nt * 16 + pl]
                    = fmaxf(acc2[mt][nt][r] + shf[r], 0.f);
    }
}

// ---------------------------------------------------------------------------
extern "C" void kernel_launch(void* const* d_in, const int* in_sizes, int n_in,
                              void* d_out, int out_size, void* d_ws, size_t ws_size,
                              hipStream_t stream)
{
    const float* query = (const float*)d_in[0];
    const float* key   = (const float*)d_in[1];
    const float* val   = (const float*)d_in[2];
    const int*   mask  = (const int*)  d_in[3];
    const float* Wq1 = (const float*)d_in[4];  const float* sq1 = (const float*)d_in[5];  const float* bq1 = (const float*)d_in[6];
    const float* Wq2 = (const float*)d_in[7];  const float* sq2 = (const float*)d_in[8];  const float* bq2 = (const float*)d_in[9];
    const float* Wk1 = (const float*)d_in[10]; const float* sk1 = (const float*)d_in[11]; const float* bk1 = (const float*)d_in[12];
    const float* Wk2 = (const float*)d_in[13]; const float* sk2 = (const float*)d_in[14]; const float* bk2 = (const float*)d_in[15];
    const float* Wv  = (const float*)d_in[16]; const float* sv  = (const float*)d_in[17]; const float* bv  = (const float*)d_in[18];
    const float* Wo  = (const float*)d_in[19]; const float* so  = (const float*)d_in[20]; const float* bo  = (const float*)d_in[21];
    const float* Wb  = (const float*)d_in[22]; const float* sb  = (const float*)d_in[23]; const float* bb  = (const float*)d_in[24];

    char* ws = (char*)d_ws;
    bf16*   kbuf = (bf16*)(ws);                        // [B][K][C] bf16  : 1 MB
    bf16*   vbuf = (bf16*)(ws + (1u << 20));           // [B][C][K] bf16  : 1 MB
    bf16*   qbuf = (bf16*)(ws + (2u << 20));           // [B][HW][C] bf16 : 16 MB
    bf16*   ctxb = (bf16*)(ws + (18u << 20));          // [B][HW][C] bf16 : 16 MB
    bf16*   qt   = (bf16*)(ws + (34u << 20));          // [B][HW][C] bf16 : 16 MB
    __bf16* Wq1p = (__bf16*)(ws + (50u << 20));                  // 32 KB
    __bf16* Wq2p = (__bf16*)(ws + (50u << 20) + (32u << 10));    // 32 KB
    __bf16* Wop  = (__bf16*)(ws + (50u << 20) + (64u << 10));    // 32 KB
    __bf16* Wbp  = (__bf16*)(ws + (50u << 20) + (96u << 10));    // 128 KB
    float* outp = (float*)d_out;

    wprep_kernel<<<448, 256, 0, stream>>>(Wq1, sq1, Wq2, sq2, Wo, so, Wb, sb,
                                          Wq1p, Wq2p, Wop, Wbp);
    tq_kernel<<<dim3(HW_ / 64, B_), 256, 0, stream>>>(query, qt);
    kv_proj_kernel<<<dim3(K_ / 32, B_), 256, 0, stream>>>(
        key, val, Wk1, sk1, bk1, Wk2, sk2, bk2, Wv, sv, bv, kbuf, vbuf);
    qproj_kernel<<<dim3(HW_ / 128, B_), 256, 0, stream>>>(
        qt, Wq1p, bq1, Wq2p, bq2, qbuf);
    attn_kernel<<<dim3(HW_ / 64, B_), 256, 0, stream>>>(
        qbuf, kbuf, vbuf, mask, ctxb);
    final_kernel<<<dim3(HW_ / 128, B_), 256, 0, stream>>>(
        ctxb, qt, Wop, bo, Wbp, bb, outp);
}